// Round 3
// baseline (15449.268 us; speedup 1.0000x reference)
//
#include <hip/hip_runtime.h>

#define N_EXC 512
#define N_INH 128
#define NTOT  640
#define NIN   16
#define NOUT  2
#define BATCH 64
#define TSTEPS 1000
// ALPHA = 0.5, NOISE_SCALE = 0.01

// ---------------------------------------------------------------------------
// JAX threefry2x32 with key = jax.random.key(42) -> (k0=0, k1=42)
// ---------------------------------------------------------------------------
__device__ __forceinline__ void threefry_0_42(unsigned x0, unsigned x1,
                                              unsigned& o0, unsigned& o1) {
    const unsigned ks0 = 0u;
    const unsigned ks1 = 42u;
    const unsigned ks2 = 0x1BD11BDAu ^ 0u ^ 42u;
    x0 += ks0; x1 += ks1;
#define TF_RND(r) { x0 += x1; x1 = (x1 << (r)) | (x1 >> (32 - (r))); x1 ^= x0; }
    TF_RND(13) TF_RND(15) TF_RND(26) TF_RND(6)
    x0 += ks1; x1 += ks2 + 1u;
    TF_RND(17) TF_RND(29) TF_RND(16) TF_RND(24)
    x0 += ks2; x1 += ks0 + 2u;
    TF_RND(13) TF_RND(15) TF_RND(26) TF_RND(6)
    x0 += ks0; x1 += ks1 + 3u;
    TF_RND(17) TF_RND(29) TF_RND(16) TF_RND(24)
    x0 += ks1; x1 += ks2 + 4u;
    TF_RND(13) TF_RND(15) TF_RND(26) TF_RND(6)
    x0 += ks2; x1 += ks0 + 5u;
#undef TF_RND
    o0 = x0; o1 = x1;
}

// JAX partitionable 32-bit random bits for flat index idx (size < 2^32):
// (hi, lo) = (0, idx); bits = out0 ^ out1
__device__ __forceinline__ unsigned jax_bits_partitionable(unsigned idx) {
    unsigned o0, o1;
    threefry_0_42(0u, idx, o0, o1);
    return o0 ^ o1;
}

// bits -> jax.random.normal sample scaled by NOISE_SCALE*sqrt(ALPHA), f32-exact
__device__ __forceinline__ float noise_from_bits(unsigned bits) {
    float f = __uint_as_float(0x3f800000u | (bits >> 9)) - 1.0f;   // [0,1), exact
    float u = __fadd_rn(__fmul_rn(f, 2.0f), -0.99999994f);         // f*2 exact
    u = fmaxf(-0.99999994f, u);
    // XLA ErfInv32 (Giles polynomial)
    float w = -log1pf(-__fmul_rn(u, u));
    float p;
    if (w < 5.0f) {
        float ww = w - 2.5f;
        p = 2.81022636e-08f;
        p = fmaf(p, ww, 3.43273939e-07f);
        p = fmaf(p, ww, -3.5233877e-06f);
        p = fmaf(p, ww, -4.39150654e-06f);
        p = fmaf(p, ww, 0.00021858087f);
        p = fmaf(p, ww, -0.00125372503f);
        p = fmaf(p, ww, -0.00417768164f);
        p = fmaf(p, ww, 0.246640727f);
        p = fmaf(p, ww, 1.50140941f);
    } else {
        float ww = sqrtf(w) - 3.0f;
        p = -0.000200214257f;
        p = fmaf(p, ww, 0.000100950558f);
        p = fmaf(p, ww, 0.00134934322f);
        p = fmaf(p, ww, -0.00367342844f);
        p = fmaf(p, ww, 0.00573950773f);
        p = fmaf(p, ww, -0.0076224613f);
        p = fmaf(p, ww, 0.00943887047f);
        p = fmaf(p, ww, 1.00167406f);
        p = fmaf(p, ww, 2.83297682f);
    }
    float z = 1.41421354f * (p * u);       // sqrt(2) * erfinv(u)
    return (0.01f * 0.70710677f) * z;      // NOISE_SCALE * sqrt(ALPHA) * z
}

// ---------------------------------------------------------------------------
// Prep: WT[k][n] = dale(W_raw)[n][k] = |W_raw[n,k]| * (k<512 ? 1 : -1) * (n!=k)
// ---------------------------------------------------------------------------
__global__ void prep_wt(const float* __restrict__ Wraw, float* __restrict__ WT) {
    __shared__ float tile[32][33];
    const int bk = blockIdx.x * 32;   // k tile
    const int bn = blockIdx.y * 32;   // n tile
    const int tx = threadIdx.x;       // 0..31
    const int ty = threadIdx.y;       // 0..7
#pragma unroll
    for (int i = 0; i < 4; ++i) {
        int nn = bn + ty + i * 8;
        tile[ty + i * 8][tx] = Wraw[nn * NTOT + bk + tx];
    }
    __syncthreads();
#pragma unroll
    for (int i = 0; i < 4; ++i) {
        int kk = bk + ty + i * 8;
        int nn = bn + tx;
        float v = fabsf(tile[tx][ty + i * 8]);
        v = (kk < N_EXC) ? v : -v;
        if (kk == nn) v = 0.0f;
        WT[kk * NTOT + nn] = v;
    }
}

// ---------------------------------------------------------------------------
// Main persistent kernel (f32 dynamics): one workgroup per batch sample,
// 640 threads, thread n owns unit n; x in a register; r broadcast via LDS.
// ---------------------------------------------------------------------------
__global__ __launch_bounds__(640, 1)
void eirnn_main(const float* __restrict__ inputs, const float* __restrict__ WT,
                const float* __restrict__ W_in, const float* __restrict__ W_out,
                const float* __restrict__ b_out, float* __restrict__ rates_out,
                float* __restrict__ outs_out) {
    const int b = blockIdx.x;
    const int n = threadIdx.x;

    __shared__ __align__(16) float r_s[NTOT];
    __shared__ float u_s[NIN];
    __shared__ float red0[16], red1[16];

    float win[NIN];
#pragma unroll
    for (int j = 0; j < NIN; ++j) win[j] = W_in[n * NIN + j];
    const float wo0 = (n < N_EXC) ? W_out[n] : 0.0f;
    const float wo1 = (n < N_EXC) ? W_out[N_EXC + n] : 0.0f;
    const float bo0 = b_out[0], bo1 = b_out[1];

    const float* inp_b = inputs    + (size_t)b * TSTEPS * NIN;
    float* rates_b     = rates_out + (size_t)b * TSTEPS * NTOT;
    float* outs_b      = outs_out  + (size_t)b * TSTEPS * NOUT;

    const int wave = n >> 6, lane = n & 63;

    float x = 0.0f;

    for (int t = 0; t < TSTEPS; ++t) {
        // rates from previous potential: softplus = max(x,0) + log1p(exp(-|x|))
        float r = fmaxf(x, 0.0f) + log1pf(expf(-fabsf(x)));
        r_s[n] = r;
        rates_b[t * NTOT + n] = r;
        if (n < NIN) u_s[n] = inp_b[t * NIN + n];

        // readout partials: y = r[:512] @ W_out.T + b_out
        float p0 = r * wo0, p1 = r * wo1;
#pragma unroll
        for (int off = 32; off; off >>= 1) {
            p0 += __shfl_down(p0, off);
            p1 += __shfl_down(p1, off);
        }
        if (lane == 0) { red0[wave] = p0; red1[wave] = p1; }

        __syncthreads();   // r_s, u_s, red visible

        if (n == 0) {
            float y0 = bo0, y1 = bo1;
#pragma unroll
            for (int w = 0; w < 10; ++w) { y0 += red0[w]; y1 += red1[w]; }
            outs_b[t * NOUT + 0] = y0;
            outs_b[t * NOUT + 1] = y1;
        }

        // recurrent input: rec[n] = sum_k WT[k][n] * r[k]   (coalesced in n)
        float acc0 = 0.f, acc1 = 0.f, acc2 = 0.f, acc3 = 0.f;
        float acc4 = 0.f, acc5 = 0.f, acc6 = 0.f, acc7 = 0.f;
        const float* wp = WT + n;
#pragma unroll 4
        for (int k0 = 0; k0 < NTOT; k0 += 8) {
            float4 ra = *(const float4*)&r_s[k0];
            float4 rb = *(const float4*)&r_s[k0 + 4];
            acc0 = fmaf(wp[(size_t)(k0 + 0) * NTOT], ra.x, acc0);
            acc1 = fmaf(wp[(size_t)(k0 + 1) * NTOT], ra.y, acc1);
            acc2 = fmaf(wp[(size_t)(k0 + 2) * NTOT], ra.z, acc2);
            acc3 = fmaf(wp[(size_t)(k0 + 3) * NTOT], ra.w, acc3);
            acc4 = fmaf(wp[(size_t)(k0 + 4) * NTOT], rb.x, acc4);
            acc5 = fmaf(wp[(size_t)(k0 + 5) * NTOT], rb.y, acc5);
            acc6 = fmaf(wp[(size_t)(k0 + 6) * NTOT], rb.z, acc6);
            acc7 = fmaf(wp[(size_t)(k0 + 7) * NTOT], rb.w, acc7);
        }
        float rec = ((acc0 + acc1) + (acc2 + acc3)) + ((acc4 + acc5) + (acc6 + acc7));

        // external input
        float ext = 0.0f;
#pragma unroll
        for (int j = 0; j < NIN; ++j) ext = fmaf(win[j], u_s[j], ext);

        // exact JAX noise (partitionable threefry) for element (t, b, n)
        unsigned idx = (unsigned)(t * (BATCH * NTOT) + b * NTOT + n);
        float eps = noise_from_bits(jax_bits_partitionable(idx));

        // x_{t+1} = 0.5*x + 0.5*(rec + ext) + eps
        x = (0.5f * x + 0.5f * (rec + ext)) + eps;

        __syncthreads();   // protect r_s/u_s before next-step overwrite
    }
}

// ---------------------------------------------------------------------------
extern "C" void kernel_launch(void* const* d_in, const int* in_sizes, int n_in,
                              void* d_out, int out_size, void* d_ws, size_t ws_size,
                              hipStream_t stream) {
    const float* inputs = (const float*)d_in[0];   // [64,1000,16]
    const float* Wraw   = (const float*)d_in[1];   // [640,640]
    const float* W_in   = (const float*)d_in[2];   // [640,16]
    const float* W_out  = (const float*)d_in[3];   // [2,512]
    const float* b_out  = (const float*)d_in[4];   // [2]

    float* out   = (float*)d_out;
    float* rates = out;                                    // [64,1000,640]
    float* outs  = out + (size_t)BATCH * TSTEPS * NTOT;    // [64,1000,2]

    float* WT = (float*)d_ws;   // 640*640 f32 = 1.6 MB scratch

    prep_wt<<<dim3(20, 20), dim3(32, 8), 0, stream>>>(Wraw, WT);
    eirnn_main<<<dim3(BATCH), dim3(NTOT), 0, stream>>>(inputs, WT, W_in, W_out,
                                                       b_out, rates, outs);
}

// Round 4
// 10894.942 us; speedup vs baseline: 1.4180x; 1.4180x over previous
//
#include <hip/hip_runtime.h>

#define N_EXC  512
#define NTOT   640
#define NIN    16
#define BATCH  64
#define TSTEPS 1000
#define CHUNK  160      // units per block
#define NBLKG  4        // blocks per batch sample
#define THREADS 512
#define NPT    5        // n per thread (32 ti-cols * 5 = 160)
#define KPT    40       // k per thread (16 tj-rows * 40 = 640)
// ALPHA = 0.5, NOISE_SCALE = 0.01

// ---------------------------------------------------------------------------
// JAX threefry2x32, key = jax.random.key(42) -> (0, 42); partitionable bits
// ---------------------------------------------------------------------------
__device__ __forceinline__ void threefry_0_42(unsigned x0, unsigned x1,
                                              unsigned& o0, unsigned& o1) {
    const unsigned ks1 = 42u;
    const unsigned ks2 = 0x1BD11BDAu ^ 42u;
    x0 += 0u; x1 += ks1;
#define TF_RND(r) { x0 += x1; x1 = (x1 << (r)) | (x1 >> (32 - (r))); x1 ^= x0; }
    TF_RND(13) TF_RND(15) TF_RND(26) TF_RND(6)
    x0 += ks1; x1 += ks2 + 1u;
    TF_RND(17) TF_RND(29) TF_RND(16) TF_RND(24)
    x0 += ks2; x1 += 0u + 2u;
    TF_RND(13) TF_RND(15) TF_RND(26) TF_RND(6)
    x0 += 0u; x1 += ks1 + 3u;
    TF_RND(17) TF_RND(29) TF_RND(16) TF_RND(24)
    x0 += ks1; x1 += ks2 + 4u;
    TF_RND(13) TF_RND(15) TF_RND(26) TF_RND(6)
    x0 += ks2; x1 += 0u + 5u;
#undef TF_RND
    o0 = x0; o1 = x1;
}

__device__ __forceinline__ unsigned jax_bits_partitionable(unsigned idx) {
    unsigned o0, o1;
    threefry_0_42(0u, idx, o0, o1);
    return o0 ^ o1;
}

// bits -> jax.random.normal sample scaled by NOISE_SCALE*sqrt(ALPHA), f32-exact
__device__ __forceinline__ float noise_from_bits(unsigned bits) {
    float f = __uint_as_float(0x3f800000u | (bits >> 9)) - 1.0f;   // [0,1)
    float u = __fadd_rn(__fmul_rn(f, 2.0f), -0.99999994f);
    u = fmaxf(-0.99999994f, u);
    float w = -log1pf(-__fmul_rn(u, u));
    float p;
    if (w < 5.0f) {
        float ww = w - 2.5f;
        p = 2.81022636e-08f;
        p = fmaf(p, ww, 3.43273939e-07f);
        p = fmaf(p, ww, -3.5233877e-06f);
        p = fmaf(p, ww, -4.39150654e-06f);
        p = fmaf(p, ww, 0.00021858087f);
        p = fmaf(p, ww, -0.00125372503f);
        p = fmaf(p, ww, -0.00417768164f);
        p = fmaf(p, ww, 0.246640727f);
        p = fmaf(p, ww, 1.50140941f);
    } else {
        float ww = sqrtf(w) - 3.0f;
        p = -0.000200214257f;
        p = fmaf(p, ww, 0.000100950558f);
        p = fmaf(p, ww, 0.00134934322f);
        p = fmaf(p, ww, -0.00367342844f);
        p = fmaf(p, ww, 0.00573950773f);
        p = fmaf(p, ww, -0.0076224613f);
        p = fmaf(p, ww, 0.00943887047f);
        p = fmaf(p, ww, 1.00167406f);
        p = fmaf(p, ww, 2.83297682f);
    }
    float z = 1.41421354f * (p * u);
    return (0.01f * 0.70710677f) * z;
}

// ---------------------------------------------------------------------------
// Persistent kernel: 256 blocks = 4 chunk-blocks x 64 batches, weights in VGPRs.
// blockIdx = g*64 + b  (batch's 4 blocks share an XCD since 64 % 8 == 0).
// Per-step cross-block rate exchange via L2 rbuf + monotone flags.
// ---------------------------------------------------------------------------
__global__ __launch_bounds__(THREADS, 2)
void eirnn_sync(const float* __restrict__ inputs, const float* __restrict__ Wraw,
                const float* __restrict__ W_in, const float* __restrict__ W_out,
                const float* __restrict__ b_out, float* __restrict__ rates_out,
                float* __restrict__ outs_out, unsigned* __restrict__ flags,
                float* __restrict__ rbuf) {
    const int b   = blockIdx.x & 63;
    const int g   = blockIdx.x >> 6;
    const int tid = threadIdx.x;
    const int ti  = tid & 31;   // n-column group
    const int tj  = tid >> 5;   // k-row group (0..15)
    const int nbase = g * CHUNK;

    __shared__ float r_all[NTOT];
    __shared__ float part[16 * CHUNK];
    __shared__ float win_s[CHUNK * 17];
    __shared__ float u_s[NIN];
    __shared__ float red0[8], red1[8];

    // ---- one-time: weight panel into registers (dale applied on the fly) ----
    float w[KPT * NPT];
#pragma unroll
    for (int c = 0; c < NPT; ++c) {
        const int n = nbase + ti * NPT + c;
#pragma unroll
        for (int kk = 0; kk < KPT; ++kk) {
            const int k = tj * KPT + kk;
            float v = fabsf(Wraw[n * NTOT + k]);
            v = (k < N_EXC) ? v : -v;
            if (k == n) v = 0.0f;
            w[kk * NPT + c] = v;
        }
    }
    // W_in chunk -> LDS (padded stride 17: conflict-free owner reads)
    for (int i = tid; i < CHUNK * NIN; i += THREADS) {
        int o = i >> 4, j = i & 15;
        win_s[o * 17 + j] = W_in[(nbase + o) * NIN + j];
    }
    // readout weights: block g==0 computes y; tid covers exactly r[:512]
    float wo0 = 0.0f, wo1 = 0.0f;
    if (g == 0) { wo0 = W_out[tid]; wo1 = W_out[N_EXC + tid]; }
    const float bo0 = b_out[0], bo1 = b_out[1];

    const float* inp_b = inputs    + (size_t)b * TSTEPS * NIN;
    float* rates_b     = rates_out + (size_t)b * TSTEPS * NTOT;
    float* outs_b      = outs_out  + (size_t)b * TSTEPS * 2;
    unsigned* myflag   = flags + (b * NBLKG + g);

    float x = 0.0f;   // owner state for tid < CHUNK
    __syncthreads();  // win_s ready

    for (int t = 0; t < TSTEPS; ++t) {
        // ---- phase A: rates from current x; publish own chunk -------------
        if (tid < CHUNK) {
            float r = fmaxf(x, 0.0f) + log1pf(expf(-fabsf(x)));
            r_all[nbase + tid] = r;
            rates_b[t * NTOT + nbase + tid] = r;
            float* dst = rbuf + ((size_t)((t & 1) * BATCH + b) * NBLKG + g) * CHUNK + tid;
            __hip_atomic_store(dst, r, __ATOMIC_RELAXED, __HIP_MEMORY_SCOPE_AGENT);
        } else if (tid < CHUNK + NIN) {
            u_s[tid - CHUNK] = inp_b[t * NIN + (tid - CHUNK)];
        }
        __syncthreads();   // drains owners' rbuf stores (vmcnt) before flag

        if (tid == 0)
            __hip_atomic_store(myflag, (unsigned)(t + 1), __ATOMIC_RELEASE,
                               __HIP_MEMORY_SCOPE_AGENT);
        if (tid >= 1 && tid < NBLKG) {          // 3 pollers
            int p = tid - 1;
            int gg = p + (p >= g ? 1 : 0);
            unsigned* f = flags + b * NBLKG + gg;
            while (__hip_atomic_load(f, __ATOMIC_ACQUIRE, __HIP_MEMORY_SCOPE_AGENT)
                   < (unsigned)(t + 1)) {
                __builtin_amdgcn_s_sleep(1);
            }
        }
        __syncthreads();

        // ---- phase B: pull remote chunks into r_all ------------------------
        if (tid < 3 * CHUNK) {
            int p = tid / CHUNK;
            int gg = p + (p >= g ? 1 : 0);
            int o = tid - p * CHUNK;
            const float* src = rbuf + ((size_t)((t & 1) * BATCH + b) * NBLKG + gg) * CHUNK + o;
            r_all[gg * CHUNK + o] =
                __hip_atomic_load(src, __ATOMIC_RELAXED, __HIP_MEMORY_SCOPE_AGENT);
        }
        __syncthreads();

        // ---- phase C: register-resident GEMV -------------------------------
        float acc[NPT] = {0.f, 0.f, 0.f, 0.f, 0.f};
#pragma unroll
        for (int kk = 0; kk < KPT; ++kk) {
            float rk = r_all[tj * KPT + kk];
#pragma unroll
            for (int c = 0; c < NPT; ++c)
                acc[c] = fmaf(w[kk * NPT + c], rk, acc[c]);
        }
#pragma unroll
        for (int c = 0; c < NPT; ++c)
            part[tj * CHUNK + ti * NPT + c] = acc[c];

        // readout partials on g==0 (r_all is complete r_t)
        if (g == 0) {
            float rr = r_all[tid];
            float p0 = rr * wo0, p1 = rr * wo1;
#pragma unroll
            for (int off = 32; off; off >>= 1) {
                p0 += __shfl_down(p0, off);
                p1 += __shfl_down(p1, off);
            }
            if ((tid & 63) == 0) { red0[tid >> 6] = p0; red1[tid >> 6] = p1; }
        }
        __syncthreads();

        // ---- phase D: owner state update ----------------------------------
        if (tid < CHUNK) {
            float rec = 0.0f;
#pragma unroll
            for (int j = 0; j < 16; ++j) rec += part[j * CHUNK + tid];
            float ext = 0.0f;
#pragma unroll
            for (int j = 0; j < NIN; ++j)
                ext = fmaf(win_s[tid * 17 + j], u_s[j], ext);
            unsigned idx = (unsigned)(t * (BATCH * NTOT) + b * NTOT + (nbase + tid));
            float eps = noise_from_bits(jax_bits_partitionable(idx));
            x = (0.5f * x + 0.5f * (rec + ext)) + eps;
        }
        if (g == 0 && tid == 0) {
            float y0 = bo0, y1 = bo1;
#pragma unroll
            for (int wv = 0; wv < 8; ++wv) { y0 += red0[wv]; y1 += red1[wv]; }
            outs_b[t * 2 + 0] = y0;
            outs_b[t * 2 + 1] = y1;
        }
        __syncthreads();   // protect r_all/part/u_s/red before next iteration
    }
}

// ---------------------------------------------------------------------------
extern "C" void kernel_launch(void* const* d_in, const int* in_sizes, int n_in,
                              void* d_out, int out_size, void* d_ws, size_t ws_size,
                              hipStream_t stream) {
    const float* inputs = (const float*)d_in[0];   // [64,1000,16]
    const float* Wraw   = (const float*)d_in[1];   // [640,640]
    const float* W_in   = (const float*)d_in[2];   // [640,16]
    const float* W_out  = (const float*)d_in[3];   // [2,512]
    const float* b_out  = (const float*)d_in[4];   // [2]

    float* out   = (float*)d_out;
    float* rates = out;                                    // [64,1000,640]
    float* outs  = out + (size_t)BATCH * TSTEPS * NTOT;    // [64,1000,2]

    unsigned* flags = (unsigned*)d_ws;                     // 64*4 u32, zeroed
    float* rbuf = (float*)((char*)d_ws + 4096);            // [2][64][4][160] f32

    hipMemsetAsync(d_ws, 0, 4096, stream);
    eirnn_sync<<<dim3(NBLKG * BATCH), dim3(THREADS), 0, stream>>>(
        inputs, Wraw, W_in, W_out, b_out, rates, outs, flags, rbuf);
}

// Round 5
// 10818.436 us; speedup vs baseline: 1.4280x; 1.0071x over previous
//
#include <hip/hip_runtime.h>

#define N_EXC  512
#define NTOT   640
#define NIN    16
#define BATCH  64
#define TSTEPS 1000
#define CHUNK  160      // units per block
#define NBLKG  4        // blocks per batch sample
#define THREADS 512
#define NPT    5        // n per thread (32 ti-cols * 5 = 160)
#define KPT    40       // k per thread (16 tj-rows * 40 = 640)
// ALPHA = 0.5, NOISE_SCALE = 0.01

// ---------------------------------------------------------------------------
// JAX threefry2x32, key = jax.random.key(42) -> (0, 42); partitionable bits
// ---------------------------------------------------------------------------
__device__ __forceinline__ void threefry_0_42(unsigned x0, unsigned x1,
                                              unsigned& o0, unsigned& o1) {
    const unsigned ks1 = 42u;
    const unsigned ks2 = 0x1BD11BDAu ^ 42u;
    x0 += 0u; x1 += ks1;
#define TF_RND(r) { x0 += x1; x1 = (x1 << (r)) | (x1 >> (32 - (r))); x1 ^= x0; }
    TF_RND(13) TF_RND(15) TF_RND(26) TF_RND(6)
    x0 += ks1; x1 += ks2 + 1u;
    TF_RND(17) TF_RND(29) TF_RND(16) TF_RND(24)
    x0 += ks2; x1 += 0u + 2u;
    TF_RND(13) TF_RND(15) TF_RND(26) TF_RND(6)
    x0 += 0u; x1 += ks1 + 3u;
    TF_RND(17) TF_RND(29) TF_RND(16) TF_RND(24)
    x0 += ks1; x1 += ks2 + 4u;
    TF_RND(13) TF_RND(15) TF_RND(26) TF_RND(6)
    x0 += ks2; x1 += 0u + 5u;
#undef TF_RND
    o0 = x0; o1 = x1;
}

__device__ __forceinline__ unsigned jax_bits_partitionable(unsigned idx) {
    unsigned o0, o1;
    threefry_0_42(0u, idx, o0, o1);
    return o0 ^ o1;
}

// bits -> jax.random.normal sample scaled by NOISE_SCALE*sqrt(ALPHA), f32-exact
__device__ __forceinline__ float noise_from_bits(unsigned bits) {
    float f = __uint_as_float(0x3f800000u | (bits >> 9)) - 1.0f;   // [0,1)
    float u = __fadd_rn(__fmul_rn(f, 2.0f), -0.99999994f);
    u = fmaxf(-0.99999994f, u);
    float w = -log1pf(-__fmul_rn(u, u));
    float p;
    if (w < 5.0f) {
        float ww = w - 2.5f;
        p = 2.81022636e-08f;
        p = fmaf(p, ww, 3.43273939e-07f);
        p = fmaf(p, ww, -3.5233877e-06f);
        p = fmaf(p, ww, -4.39150654e-06f);
        p = fmaf(p, ww, 0.00021858087f);
        p = fmaf(p, ww, -0.00125372503f);
        p = fmaf(p, ww, -0.00417768164f);
        p = fmaf(p, ww, 0.246640727f);
        p = fmaf(p, ww, 1.50140941f);
    } else {
        float ww = sqrtf(w) - 3.0f;
        p = -0.000200214257f;
        p = fmaf(p, ww, 0.000100950558f);
        p = fmaf(p, ww, 0.00134934322f);
        p = fmaf(p, ww, -0.00367342844f);
        p = fmaf(p, ww, 0.00573950773f);
        p = fmaf(p, ww, -0.0076224613f);
        p = fmaf(p, ww, 0.00943887047f);
        p = fmaf(p, ww, 1.00167406f);
        p = fmaf(p, ww, 2.83297682f);
    }
    float z = 1.41421354f * (p * u);
    return (0.01f * 0.70710677f) * z;
}

// ---------------------------------------------------------------------------
// Persistent kernel: 256 blocks = 4 chunk-blocks x 64 batches, weights in VGPRs.
// __launch_bounds__(512, 1): HIP 2nd arg = min BLOCKS/CU (CUDA semantics).
// 1 block/CU -> 8 waves/CU = 2 waves/SIMD -> 256-VGPR cap; w[200] fits, no spill.
// (Round 4's (512,2) forced a 128-VGPR cap and spilled w[] to scratch.)
// ---------------------------------------------------------------------------
__global__ __launch_bounds__(THREADS, 1)
void eirnn_sync(const float* __restrict__ inputs, const float* __restrict__ Wraw,
                const float* __restrict__ W_in, const float* __restrict__ W_out,
                const float* __restrict__ b_out, float* __restrict__ rates_out,
                float* __restrict__ outs_out, unsigned* __restrict__ flags,
                float* __restrict__ rbuf) {
    const int b   = blockIdx.x & 63;
    const int g   = blockIdx.x >> 6;
    const int tid = threadIdx.x;
    const int ti  = tid & 31;   // n-column group
    const int tj  = tid >> 5;   // k-row group (0..15)
    const int nbase = g * CHUNK;

    __shared__ float r_all[NTOT];
    __shared__ float part[16 * CHUNK];
    __shared__ float win_s[CHUNK * 17];
    __shared__ float u_s[NIN];
    __shared__ float red0[8], red1[8];

    // ---- one-time: weight panel into registers (dale applied on the fly) ----
    float w[KPT * NPT];
#pragma unroll
    for (int c = 0; c < NPT; ++c) {
        const int n = nbase + ti * NPT + c;
#pragma unroll
        for (int kk = 0; kk < KPT; ++kk) {
            const int k = tj * KPT + kk;
            float v = fabsf(Wraw[n * NTOT + k]);
            v = (k < N_EXC) ? v : -v;
            if (k == n) v = 0.0f;
            w[kk * NPT + c] = v;
        }
    }
    // W_in chunk -> LDS (padded stride 17: conflict-free owner reads)
    for (int i = tid; i < CHUNK * NIN; i += THREADS) {
        int o = i >> 4, j = i & 15;
        win_s[o * 17 + j] = W_in[(nbase + o) * NIN + j];
    }
    // readout weights: block g==0 computes y; tid covers exactly r[:512]
    float wo0 = 0.0f, wo1 = 0.0f;
    if (g == 0) { wo0 = W_out[tid]; wo1 = W_out[N_EXC + tid]; }
    const float bo0 = b_out[0], bo1 = b_out[1];

    const float* inp_b = inputs    + (size_t)b * TSTEPS * NIN;
    float* rates_b     = rates_out + (size_t)b * TSTEPS * NTOT;
    float* outs_b      = outs_out  + (size_t)b * TSTEPS * 2;
    unsigned* myflag   = flags + (b * NBLKG + g);

    float x = 0.0f;   // owner state for tid < CHUNK
    __syncthreads();  // win_s ready

    for (int t = 0; t < TSTEPS; ++t) {
        // ---- phase A: rates from current x; publish own chunk -------------
        if (tid < CHUNK) {
            float r = fmaxf(x, 0.0f) + log1pf(expf(-fabsf(x)));
            r_all[nbase + tid] = r;
            rates_b[t * NTOT + nbase + tid] = r;
            float* dst = rbuf + ((size_t)((t & 1) * BATCH + b) * NBLKG + g) * CHUNK + tid;
            __hip_atomic_store(dst, r, __ATOMIC_RELAXED, __HIP_MEMORY_SCOPE_AGENT);
        } else if (tid < CHUNK + NIN) {
            u_s[tid - CHUNK] = inp_b[t * NIN + (tid - CHUNK)];
        }
        __syncthreads();   // drains owners' rbuf stores (vmcnt) before flag

        if (tid == 0)
            __hip_atomic_store(myflag, (unsigned)(t + 1), __ATOMIC_RELEASE,
                               __HIP_MEMORY_SCOPE_AGENT);
        if (tid >= 1 && tid < NBLKG) {          // 3 pollers
            int p = tid - 1;
            int gg = p + (p >= g ? 1 : 0);
            unsigned* f = flags + b * NBLKG + gg;
            while (__hip_atomic_load(f, __ATOMIC_ACQUIRE, __HIP_MEMORY_SCOPE_AGENT)
                   < (unsigned)(t + 1)) {
                __builtin_amdgcn_s_sleep(1);
            }
        }
        __syncthreads();

        // ---- phase B: pull remote chunks into r_all ------------------------
        if (tid < 3 * CHUNK) {
            int p = tid / CHUNK;
            int gg = p + (p >= g ? 1 : 0);
            int o = tid - p * CHUNK;
            const float* src = rbuf + ((size_t)((t & 1) * BATCH + b) * NBLKG + gg) * CHUNK + o;
            r_all[gg * CHUNK + o] =
                __hip_atomic_load(src, __ATOMIC_RELAXED, __HIP_MEMORY_SCOPE_AGENT);
        }
        __syncthreads();

        // ---- phase C: register-resident GEMV -------------------------------
        float acc[NPT] = {0.f, 0.f, 0.f, 0.f, 0.f};
#pragma unroll
        for (int kk = 0; kk < KPT; ++kk) {
            float rk = r_all[tj * KPT + kk];
#pragma unroll
            for (int c = 0; c < NPT; ++c)
                acc[c] = fmaf(w[kk * NPT + c], rk, acc[c]);
        }
#pragma unroll
        for (int c = 0; c < NPT; ++c)
            part[tj * CHUNK + ti * NPT + c] = acc[c];

        // readout partials on g==0 (r_all is complete r_t)
        if (g == 0) {
            float rr = r_all[tid];
            float p0 = rr * wo0, p1 = rr * wo1;
#pragma unroll
            for (int off = 32; off; off >>= 1) {
                p0 += __shfl_down(p0, off);
                p1 += __shfl_down(p1, off);
            }
            if ((tid & 63) == 0) { red0[tid >> 6] = p0; red1[tid >> 6] = p1; }
        }
        __syncthreads();

        // ---- phase D: owner state update ----------------------------------
        if (tid < CHUNK) {
            float rec = 0.0f;
#pragma unroll
            for (int j = 0; j < 16; ++j) rec += part[j * CHUNK + tid];
            float ext = 0.0f;
#pragma unroll
            for (int j = 0; j < NIN; ++j)
                ext = fmaf(win_s[tid * 17 + j], u_s[j], ext);
            unsigned idx = (unsigned)(t * (BATCH * NTOT) + b * NTOT + (nbase + tid));
            float eps = noise_from_bits(jax_bits_partitionable(idx));
            x = (0.5f * x + 0.5f * (rec + ext)) + eps;
        }
        if (g == 0 && tid == 0) {
            float y0 = bo0, y1 = bo1;
#pragma unroll
            for (int wv = 0; wv < 8; ++wv) { y0 += red0[wv]; y1 += red1[wv]; }
            outs_b[t * 2 + 0] = y0;
            outs_b[t * 2 + 1] = y1;
        }
        __syncthreads();   // protect r_all/part/u_s/red before next iteration
    }
}

// ---------------------------------------------------------------------------
extern "C" void kernel_launch(void* const* d_in, const int* in_sizes, int n_in,
                              void* d_out, int out_size, void* d_ws, size_t ws_size,
                              hipStream_t stream) {
    const float* inputs = (const float*)d_in[0];   // [64,1000,16]
    const float* Wraw   = (const float*)d_in[1];   // [640,640]
    const float* W_in   = (const float*)d_in[2];   // [640,16]
    const float* W_out  = (const float*)d_in[3];   // [2,512]
    const float* b_out  = (const float*)d_in[4];   // [2]

    float* out   = (float*)d_out;
    float* rates = out;                                    // [64,1000,640]
    float* outs  = out + (size_t)BATCH * TSTEPS * NTOT;    // [64,1000,2]

    unsigned* flags = (unsigned*)d_ws;                     // 64*4 u32, zeroed
    float* rbuf = (float*)((char*)d_ws + 4096);            // [2][64][4][160] f32

    hipMemsetAsync(d_ws, 0, 4096, stream);
    eirnn_sync<<<dim3(NBLKG * BATCH), dim3(THREADS), 0, stream>>>(
        inputs, Wraw, W_in, W_out, b_out, rates, outs, flags, rbuf);
}